// Round 14
// baseline (266.859 us; speedup 1.0000x reference)
//
#include <hip/hip_runtime.h>
#include <cstddef>

#define HH   256   // HEADS*HID
#define OUTC 64
#define NEG  0.2f

typedef _Float16 half8  __attribute__((ext_vector_type(8)));
typedef _Float16 half4v __attribute__((ext_vector_type(4)));
typedef float    f32x4  __attribute__((ext_vector_type(4)));
typedef unsigned short u16;

// ---------------- CSR build ----------------

// histogram + folded weight transpose/casts
__global__ __launch_bounds__(256) void hist_cast(const int* __restrict__ ei, int E, int N,
                                                 const float* __restrict__ W1,
                                                 const float* __restrict__ W2,
                                                 _Float16* __restrict__ W1t,
                                                 _Float16* __restrict__ W2t,
                                                 int* __restrict__ deg) {
    int i = blockIdx.x * 256 + threadIdx.x;
    int tot = E + N;
    if (i < tot) {
        int dst = (i < E) ? ei[E + i] : (i - E);   // self-loop for i>=E
        atomicAdd(&deg[dst], 1);
    }
    const int n1 = 128 * HH, n2 = HH * OUTC;
    if (i < n1 + n2) {
        if (i < n1) { int nn = i / 128, k = i - nn * 128; W1t[i] = (_Float16)W1[(size_t)k * HH + nn]; }
        else { int j = i - n1; int nn = j / HH, k = j - nn * HH; W2t[j] = (_Float16)W2[(size_t)k * OUTC + nn]; }
    }
}

__global__ __launch_bounds__(256) void scan_block(const int* __restrict__ deg,
                                                  int* __restrict__ offs,
                                                  int* __restrict__ part, int n) {
    __shared__ int sh[256];
    int t = threadIdx.x;
    int i = blockIdx.x * 256 + t;
    int v = (i < n) ? deg[i] : 0;
    sh[t] = v;
    __syncthreads();
    for (int off = 1; off < 256; off <<= 1) {
        int x = (t >= off) ? sh[t - off] : 0;
        __syncthreads();
        sh[t] += x;
        __syncthreads();
    }
    if (i < n) offs[i + 1] = sh[t];
    if (t == 255) part[blockIdx.x] = sh[255];
}

// merged: each block redundantly scans part[] (nb<=256), applies prefix, writes cursor
__global__ __launch_bounds__(256) void scan_finish(int* __restrict__ offs,
                                                   int* __restrict__ cursor,
                                                   const int* __restrict__ deg,
                                                   const int* __restrict__ part,
                                                   int n, int nb) {
    __shared__ int sh[256];
    int t = threadIdx.x, bid = blockIdx.x;
    sh[t] = (t < nb) ? part[t] : 0;
    __syncthreads();
    for (int off = 1; off < 256; off <<= 1) {
        int x = (t >= off) ? sh[t - off] : 0;
        __syncthreads();
        sh[t] += x;
        __syncthreads();
    }
    int excl = (bid == 0) ? 0 : sh[bid - 1];
    int i = bid * 256 + t;
    if (i < n) {
        int v = offs[i + 1] + excl;
        offs[i + 1] = v;
        cursor[i] = v - deg[i];
    }
    if (i == 0) offs[0] = 0;
}

// standalone scatter: 4 VGPR, max occupancy (fusing with GEMM cost 2x — r13)
__global__ __launch_bounds__(256) void scatter_kernel(const int* __restrict__ ei, int E, int N,
                                                      int* __restrict__ cursor,
                                                      u16* __restrict__ esrc) {
    int i = blockIdx.x * blockDim.x + threadIdx.x;
    int tot = E + N;
    if (i >= tot) return;
    int src, dst;
    if (i < E) { src = ei[i]; dst = ei[E + i]; }
    else       { src = dst = i - E; }
    int pos = atomicAdd(&cursor[dst], 1);
    esrc[pos] = (u16)src;
}

// ---------------- MFMA fp16 GEMM (swapped operands, fused score epilogue, r8-proven) ----------------

template <int K, int NT, int HEADS, bool AF32>
__global__ __launch_bounds__(256) void mfma_gemm(const void* __restrict__ Av,
                                                 const _Float16* __restrict__ Bt,
                                                 _Float16* __restrict__ C,
                                                 const float* __restrict__ atts,
                                                 const float* __restrict__ attd,
                                                 float* __restrict__ as_,
                                                 float* __restrict__ ad_,
                                                 int M) {
    constexpr int N = NT * 16;
    int t = threadIdx.x;
    int w = t >> 6, l = t & 63;
    int lm = l & 15, lk = l >> 4;
    int row0 = blockIdx.x * 64 + w * 16;
    int rowv = row0 + lm;
    int rA = rowv; if (rA >= M) rA = M - 1;
    int kOff = lk * 8;

    f32x4 acc[NT];
#pragma unroll
    for (int i = 0; i < NT; ++i) acc[i] = (f32x4){0.f, 0.f, 0.f, 0.f};

    const float*    Af = (const float*)Av    + (size_t)rA * K + kOff;
    const _Float16* Ah = (const _Float16*)Av + (size_t)rA * K + kOff;
    const _Float16* Bp = Bt + (size_t)lm * K + kOff;

#pragma unroll 1
    for (int ks = 0; ks < K / 32; ++ks) {
        half8 a;
        if constexpr (AF32) {
            float4 a0 = *(const float4*)(Af + ks * 32);
            float4 a1 = *(const float4*)(Af + ks * 32 + 4);
            a = (half8){(_Float16)a0.x, (_Float16)a0.y, (_Float16)a0.z, (_Float16)a0.w,
                        (_Float16)a1.x, (_Float16)a1.y, (_Float16)a1.z, (_Float16)a1.w};
        } else {
            a = *(const half8*)(Ah + ks * 32);
        }
#pragma unroll
        for (int nt = 0; nt < NT; ++nt) {
            half8 b = *(const half8*)(Bp + (size_t)nt * 16 * K + ks * 32);
            acc[nt] = __builtin_amdgcn_mfma_f32_16x16x32_f16(b, a, acc[nt], 0, 0, 0);
        }
    }

    if (rowv < M) {
#pragma unroll
        for (int nt = 0; nt < NT; ++nt) {
            half4v cv = {(_Float16)acc[nt][0], (_Float16)acc[nt][1],
                         (_Float16)acc[nt][2], (_Float16)acc[nt][3]};
            *(half4v*)(C + (size_t)rowv * N + nt * 16 + lk * 4) = cv;
        }
    }

    constexpr int TPH = NT / HEADS;
#pragma unroll
    for (int hh = 0; hh < HEADS; ++hh) {
        float ps = 0.f, pd = 0.f;
#pragma unroll
        for (int q = 0; q < TPH; ++q) {
            int nt = hh * TPH + q;
            float4 s4 = *(const float4*)(atts + nt * 16 + lk * 4);
            float4 d4 = *(const float4*)(attd + nt * 16 + lk * 4);
            ps += acc[nt][0] * s4.x + acc[nt][1] * s4.y + acc[nt][2] * s4.z + acc[nt][3] * s4.w;
            pd += acc[nt][0] * d4.x + acc[nt][1] * d4.y + acc[nt][2] * d4.z + acc[nt][3] * d4.w;
        }
        ps += __shfl_xor(ps, 16); ps += __shfl_xor(ps, 32);
        pd += __shfl_xor(pd, 16); pd += __shfl_xor(pd, 32);
        if (l < 16 && rowv < M) {
            as_[(size_t)rowv * HEADS + hh] = ps;
            ad_[(size_t)rowv * HEADS + hh] = pd;
        }
    }
}

// ---------------- layer-1 aggregation (r8-proven shape, u16 esrc) ----------------

__global__ __launch_bounds__(256) void agg1_kernel(const int* __restrict__ offs,
                                                   const u16* __restrict__ esrc,
                                                   const float* __restrict__ as_,
                                                   const float* __restrict__ ad_,
                                                   const _Float16* __restrict__ h,
                                                   const float* __restrict__ bias,
                                                   _Float16* __restrict__ o1h) {
    int n = blockIdx.x * 4 + (threadIdx.x >> 6);
    int l = threadIdx.x & 63;
    int beg = offs[n], deg = offs[n + 1] - beg;
    int hA = l & 7, j = l >> 3;     // score phase: slot j, head hA
    int cg = l & 31;                // channel group: channels cg*8..+7
    int hB = cg >> 2;               // head owning those channels
    int rs = l >> 5;                // row parity (even/odd slots)
    float adh = ad_[n * 8 + hA];

    float ex_c = 0.f; int s_c = 0;
    if (j < deg) {
        s_c = esrc[beg + j];
        float e = as_[s_c * 8 + hA] + adh;
        e = (e > 0.f) ? e : NEG * e;
        ex_c = __expf(e);
    }

    float acc[8] = {0.f, 0.f, 0.f, 0.f, 0.f, 0.f, 0.f, 0.f};
    float dsum = 0.f;
    for (int cs = 0; cs < deg; cs += 8) {
        float ex_n = 0.f; int s_n = 0;
        int inext = cs + 8 + j;
        if (inext < deg) {
            s_n = esrc[beg + inext];
            float e = as_[s_n * 8 + hA] + adh;
            e = (e > 0.f) ? e : NEG * e;
            ex_n = __expf(e);
        }
        dsum += ex_c;
        int lim = deg - cs;
        if (lim >= 8) {
#pragma unroll
            for (int it = 0; it < 4; ++it) {
                int slot = it * 2 + rs;
                int s2 = __shfl(s_c, slot * 8);
                float wgt = __shfl(ex_c, slot * 8 + hB);
                half8 hv = *(const half8*)(h + (size_t)s2 * HH + cg * 8);
#pragma unroll
                for (int q = 0; q < 8; ++q) acc[q] += wgt * (float)hv[q];
            }
        } else {
            int itmax = (lim + 1) >> 1;             // wave-uniform
            for (int it = 0; it < itmax; ++it) {
                int slot = it * 2 + rs;
                int s2 = __shfl(s_c, slot * 8);     // all lanes execute
                float wgt = __shfl(ex_c, slot * 8 + hB);
                if (slot < lim) {
                    half8 hv = *(const half8*)(h + (size_t)s2 * HH + cg * 8);
#pragma unroll
                    for (int q = 0; q < 8; ++q) acc[q] += wgt * (float)hv[q];
                }
            }
        }
        ex_c = ex_n; s_c = s_n;
    }
#pragma unroll
    for (int q = 0; q < 8; ++q) acc[q] += __shfl_xor(acc[q], 32);
    dsum += __shfl_xor(dsum, 8); dsum += __shfl_xor(dsum, 16); dsum += __shfl_xor(dsum, 32);
    float denom = __shfl(dsum, hB);
    float inv = 1.f / (denom + 1e-16f);
    if (l < 32) {
        half8 o;
#pragma unroll
        for (int q = 0; q < 8; ++q) {
            float v = acc[q] * inv + bias[cg * 8 + q];
            o[q] = (_Float16)fmaxf(v, 0.f);     // bias + ReLU fused, fp16 out
        }
        *(half8*)(o1h + (size_t)n * HH + cg * 8) = o;
    }
}

// ---------------- layer-2 aggregation (r9/r10-proven, u16 esrc) ----------------

__global__ __launch_bounds__(256) void agg2_kernel(const int* __restrict__ offs,
                                                   const u16* __restrict__ esrc,
                                                   const float* __restrict__ as_,
                                                   const float* __restrict__ ad_,
                                                   const _Float16* __restrict__ h,
                                                   const float* __restrict__ bias,
                                                   float* __restrict__ out) {
    int n = blockIdx.x * 4 + (threadIdx.x >> 6);
    int l = threadIdx.x & 63;
    int beg = offs[n], deg = offs[n + 1] - beg;
    float adn = ad_[n];
    int slot8 = l >> 3;
    int cq = l & 7;

    float ex_c = 0.f; int s_c = 0;
    if (l < deg) {
        s_c = esrc[beg + l];
        float e = as_[s_c] + adn;
        e = (e > 0.f) ? e : NEG * e;
        ex_c = __expf(e);
    }

    float acc[8] = {0.f, 0.f, 0.f, 0.f, 0.f, 0.f, 0.f, 0.f};
    float dsum = 0.f;
    for (int cs = 0; cs < deg; cs += 64) {
        float ex_n = 0.f; int s_n = 0;
        int inext = cs + 64 + l;
        if (inext < deg) {
            s_n = esrc[beg + inext];
            float e = as_[s_n] + adn;
            e = (e > 0.f) ? e : NEG * e;
            ex_n = __expf(e);
        }
        dsum += ex_c;
        int lim = deg - cs; if (lim > 64) lim = 64;
        if (lim >= 64) {
#pragma unroll
            for (int g = 0; g < 8; ++g) {
                int slot = g * 8 + slot8;
                int s2 = __shfl(s_c, slot);
                float wgt = __shfl(ex_c, slot);
                half8 hv = *(const half8*)(h + (size_t)s2 * OUTC + cq * 8);
#pragma unroll
                for (int q = 0; q < 8; ++q) acc[q] += wgt * (float)hv[q];
            }
        } else {
            int gmax = (lim + 7) >> 3;              // wave-uniform
            for (int g = 0; g < gmax; ++g) {
                int slot = g * 8 + slot8;
                int s2 = __shfl(s_c, slot);         // all lanes execute
                float wgt = __shfl(ex_c, slot);
                if (slot < lim) {
                    half8 hv = *(const half8*)(h + (size_t)s2 * OUTC + cq * 8);
#pragma unroll
                    for (int q = 0; q < 8; ++q) acc[q] += wgt * (float)hv[q];
                }
            }
        }
        ex_c = ex_n; s_c = s_n;
    }
#pragma unroll
    for (int q = 0; q < 8; ++q) {
        acc[q] += __shfl_xor(acc[q], 8);
        acc[q] += __shfl_xor(acc[q], 16);
        acc[q] += __shfl_xor(acc[q], 32);
    }
    dsum += __shfl_xor(dsum, 1); dsum += __shfl_xor(dsum, 2); dsum += __shfl_xor(dsum, 4);
    dsum += __shfl_xor(dsum, 8); dsum += __shfl_xor(dsum, 16); dsum += __shfl_xor(dsum, 32);
    float inv = 1.f / (dsum + 1e-16f);
    if (l < 8) {
        int c0 = l * 8;
        float4 o0, o1;
        o0.x = acc[0] * inv + bias[c0 + 0];
        o0.y = acc[1] * inv + bias[c0 + 1];
        o0.z = acc[2] * inv + bias[c0 + 2];
        o0.w = acc[3] * inv + bias[c0 + 3];
        o1.x = acc[4] * inv + bias[c0 + 4];
        o1.y = acc[5] * inv + bias[c0 + 5];
        o1.z = acc[6] * inv + bias[c0 + 6];
        o1.w = acc[7] * inv + bias[c0 + 7];
        *(float4*)(out + (size_t)n * OUTC + c0) = o0;
        *(float4*)(out + (size_t)n * OUTC + c0 + 4) = o1;
    }
}

// ---------------- launcher ----------------

extern "C" void kernel_launch(void* const* d_in, const int* in_sizes, int n_in,
                              void* d_out, int out_size, void* d_ws, size_t ws_size,
                              hipStream_t stream) {
    const float* x    = (const float*)d_in[0];
    const int*   ei   = (const int*)d_in[1];
    const float* W1   = (const float*)d_in[2];
    const float* as1w = (const float*)d_in[3];
    const float* ad1w = (const float*)d_in[4];
    const float* b1   = (const float*)d_in[5];
    const float* W2   = (const float*)d_in[6];
    const float* as2w = (const float*)d_in[7];
    const float* ad2w = (const float*)d_in[8];
    const float* b2   = (const float*)d_in[9];
    float* out = (float*)d_out;

    int N = in_sizes[0] / 128;
    int E = in_sizes[1] / 2;
    int Etot = E + N;
    int nb = (N + 255) / 256;
    int MB = (N + 63) / 64;

    char* p = (char*)d_ws;
    auto alloc = [&](size_t bytes) { char* r = p; p += (bytes + 255) & ~(size_t)255; return r; };
    _Float16* h1  = (_Float16*)alloc((size_t)N * HH * 2);
    _Float16* o1h = (_Float16*)alloc((size_t)N * HH * 2);
    _Float16* h2  = (_Float16*)alloc((size_t)N * OUTC * 2);
    _Float16* W1t = (_Float16*)alloc((size_t)128 * HH * 2);
    _Float16* W2t = (_Float16*)alloc((size_t)HH * OUTC * 2);
    float* a_s1 = (float*)alloc((size_t)N * 8 * 4);
    float* a_d1 = (float*)alloc((size_t)N * 8 * 4);
    float* a_s2 = (float*)alloc((size_t)N * 4);
    float* a_d2 = (float*)alloc((size_t)N * 4);
    int* deg    = (int*)  alloc((size_t)N * 4);
    int* offs   = (int*)  alloc((size_t)(N + 1) * 4);
    int* cursor = (int*)  alloc((size_t)N * 4);
    int* part   = (int*)  alloc(256 * 4);
    u16* esrc   = (u16*)  alloc((size_t)Etot * 2);

    // CSR by destination (includes self-loops); weight casts folded into hist
    hipMemsetAsync(deg, 0, sizeof(int) * N, stream);
    hist_cast<<<(Etot + 255) / 256, 256, 0, stream>>>(ei, E, N, W1, W2, W1t, W2t, deg);
    scan_block<<<nb, 256, 0, stream>>>(deg, offs, part, N);
    scan_finish<<<nb, 256, 0, stream>>>(offs, cursor, deg, part, N, nb);
    scatter_kernel<<<(Etot + 255) / 256, 256, 0, stream>>>(ei, E, N, cursor, esrc);

    // layer 1: GEMM (scores fused) -> aggregate (bias+ReLU fused, fp16 out)
    mfma_gemm<128, 16, 8, true><<<MB, 256, 0, stream>>>(x, W1t, h1, as1w, ad1w, a_s1, a_d1, N);
    agg1_kernel<<<N / 4, 256, 0, stream>>>(offs, esrc, a_s1, a_d1, h1, b1, o1h);

    // layer 2
    mfma_gemm<256, 4, 1, false><<<MB, 256, 0, stream>>>(o1h, W2t, h2, as2w, ad2w, a_s2, a_d2, N);
    agg2_kernel<<<N / 4, 256, 0, stream>>>(offs, esrc, a_s2, a_d2, h2, b2, out);
}

// Round 15
// 235.209 us; speedup vs baseline: 1.1346x; 1.1346x over previous
//
#include <hip/hip_runtime.h>
#include <cstddef>

#define HH   256   // HEADS*HID
#define OUTC 64
#define NEG  0.2f

typedef _Float16 half8  __attribute__((ext_vector_type(8)));
typedef _Float16 half4v __attribute__((ext_vector_type(4)));
typedef float    f32x4  __attribute__((ext_vector_type(4)));
typedef unsigned short u16;

// ---------------- CSR build ----------------

// histogram (atomic return value = edge's rank in its dst segment) + weight casts
__global__ __launch_bounds__(256) void hist_cast(const int* __restrict__ ei, int E, int N,
                                                 const float* __restrict__ W1,
                                                 const float* __restrict__ W2,
                                                 _Float16* __restrict__ W1t,
                                                 _Float16* __restrict__ W2t,
                                                 int* __restrict__ deg,
                                                 u16* __restrict__ rank) {
    int i = blockIdx.x * 256 + threadIdx.x;
    int tot = E + N;
    if (i < tot) {
        int dst = (i < E) ? ei[E + i] : (i - E);   // self-loop for i>=E
        int old = atomicAdd(&deg[dst], 1);
        rank[i] = (u16)old;                         // coalesced store of rank
    }
    const int n1 = 128 * HH, n2 = HH * OUTC;
    if (i < n1 + n2) {
        if (i < n1) { int nn = i / 128, k = i - nn * 128; W1t[i] = (_Float16)W1[(size_t)k * HH + nn]; }
        else { int j = i - n1; int nn = j / HH, k = j - nn * HH; W2t[j] = (_Float16)W2[(size_t)k * OUTC + nn]; }
    }
}

__global__ __launch_bounds__(256) void scan_block(const int* __restrict__ deg,
                                                  int* __restrict__ offs,
                                                  int* __restrict__ part, int n) {
    __shared__ int sh[256];
    int t = threadIdx.x;
    int i = blockIdx.x * 256 + t;
    int v = (i < n) ? deg[i] : 0;
    sh[t] = v;
    __syncthreads();
    for (int off = 1; off < 256; off <<= 1) {
        int x = (t >= off) ? sh[t - off] : 0;
        __syncthreads();
        sh[t] += x;
        __syncthreads();
    }
    if (i < n) offs[i + 1] = sh[t];
    if (t == 255) part[blockIdx.x] = sh[255];
}

// merged: each block redundantly scans part[] (nb<=256), applies prefix
__global__ __launch_bounds__(256) void scan_finish(int* __restrict__ offs,
                                                   const int* __restrict__ part,
                                                   int n, int nb) {
    __shared__ int sh[256];
    int t = threadIdx.x, bid = blockIdx.x;
    sh[t] = (t < nb) ? part[t] : 0;
    __syncthreads();
    for (int off = 1; off < 256; off <<= 1) {
        int x = (t >= off) ? sh[t - off] : 0;
        __syncthreads();
        sh[t] += x;
        __syncthreads();
    }
    int excl = (bid == 0) ? 0 : sh[bid - 1];
    int i = bid * 256 + t;
    if (i < n) offs[i + 1] += excl;
    if (i == 0) offs[0] = 0;
}

// atomic-FREE scatter: pos = offs[dst] + rank[i]  (rank captured in hist_cast)
__global__ __launch_bounds__(256) void scatter_kernel(const int* __restrict__ ei, int E, int N,
                                                      const int* __restrict__ offs,
                                                      const u16* __restrict__ rank,
                                                      u16* __restrict__ esrc) {
    int i = blockIdx.x * blockDim.x + threadIdx.x;
    int tot = E + N;
    if (i >= tot) return;
    int src, dst;
    if (i < E) { src = ei[i]; dst = ei[E + i]; }
    else       { src = dst = i - E; }
    int pos = offs[dst] + rank[i];
    esrc[pos] = (u16)src;
}

// ---------------- MFMA fp16 GEMM (swapped operands, fused score epilogue, r8-proven) ----------------

template <int K, int NT, int HEADS, bool AF32>
__global__ __launch_bounds__(256) void mfma_gemm(const void* __restrict__ Av,
                                                 const _Float16* __restrict__ Bt,
                                                 _Float16* __restrict__ C,
                                                 const float* __restrict__ atts,
                                                 const float* __restrict__ attd,
                                                 float* __restrict__ as_,
                                                 float* __restrict__ ad_,
                                                 int M) {
    constexpr int N = NT * 16;
    int t = threadIdx.x;
    int w = t >> 6, l = t & 63;
    int lm = l & 15, lk = l >> 4;
    int row0 = blockIdx.x * 64 + w * 16;
    int rowv = row0 + lm;
    int rA = rowv; if (rA >= M) rA = M - 1;
    int kOff = lk * 8;

    f32x4 acc[NT];
#pragma unroll
    for (int i = 0; i < NT; ++i) acc[i] = (f32x4){0.f, 0.f, 0.f, 0.f};

    const float*    Af = (const float*)Av    + (size_t)rA * K + kOff;
    const _Float16* Ah = (const _Float16*)Av + (size_t)rA * K + kOff;
    const _Float16* Bp = Bt + (size_t)lm * K + kOff;

#pragma unroll 1
    for (int ks = 0; ks < K / 32; ++ks) {
        half8 a;
        if constexpr (AF32) {
            float4 a0 = *(const float4*)(Af + ks * 32);
            float4 a1 = *(const float4*)(Af + ks * 32 + 4);
            a = (half8){(_Float16)a0.x, (_Float16)a0.y, (_Float16)a0.z, (_Float16)a0.w,
                        (_Float16)a1.x, (_Float16)a1.y, (_Float16)a1.z, (_Float16)a1.w};
        } else {
            a = *(const half8*)(Ah + ks * 32);
        }
#pragma unroll
        for (int nt = 0; nt < NT; ++nt) {
            half8 b = *(const half8*)(Bp + (size_t)nt * 16 * K + ks * 32);
            acc[nt] = __builtin_amdgcn_mfma_f32_16x16x32_f16(b, a, acc[nt], 0, 0, 0);
        }
    }

    if (rowv < M) {
#pragma unroll
        for (int nt = 0; nt < NT; ++nt) {
            half4v cv = {(_Float16)acc[nt][0], (_Float16)acc[nt][1],
                         (_Float16)acc[nt][2], (_Float16)acc[nt][3]};
            *(half4v*)(C + (size_t)rowv * N + nt * 16 + lk * 4) = cv;
        }
    }

    constexpr int TPH = NT / HEADS;
#pragma unroll
    for (int hh = 0; hh < HEADS; ++hh) {
        float ps = 0.f, pd = 0.f;
#pragma unroll
        for (int q = 0; q < TPH; ++q) {
            int nt = hh * TPH + q;
            float4 s4 = *(const float4*)(atts + nt * 16 + lk * 4);
            float4 d4 = *(const float4*)(attd + nt * 16 + lk * 4);
            ps += acc[nt][0] * s4.x + acc[nt][1] * s4.y + acc[nt][2] * s4.z + acc[nt][3] * s4.w;
            pd += acc[nt][0] * d4.x + acc[nt][1] * d4.y + acc[nt][2] * d4.z + acc[nt][3] * d4.w;
        }
        ps += __shfl_xor(ps, 16); ps += __shfl_xor(ps, 32);
        pd += __shfl_xor(pd, 16); pd += __shfl_xor(pd, 32);
        if (l < 16 && rowv < M) {
            as_[(size_t)rowv * HEADS + hh] = ps;
            ad_[(size_t)rowv * HEADS + hh] = pd;
        }
    }
}

// ---------------- layer-1 aggregation (r8-proven shape, u16 esrc) ----------------

__global__ __launch_bounds__(256) void agg1_kernel(const int* __restrict__ offs,
                                                   const u16* __restrict__ esrc,
                                                   const float* __restrict__ as_,
                                                   const float* __restrict__ ad_,
                                                   const _Float16* __restrict__ h,
                                                   const float* __restrict__ bias,
                                                   _Float16* __restrict__ o1h) {
    int n = blockIdx.x * 4 + (threadIdx.x >> 6);
    int l = threadIdx.x & 63;
    int beg = offs[n], deg = offs[n + 1] - beg;
    int hA = l & 7, j = l >> 3;     // score phase: slot j, head hA
    int cg = l & 31;                // channel group: channels cg*8..+7
    int hB = cg >> 2;               // head owning those channels
    int rs = l >> 5;                // row parity (even/odd slots)
    float adh = ad_[n * 8 + hA];

    float ex_c = 0.f; int s_c = 0;
    if (j < deg) {
        s_c = esrc[beg + j];
        float e = as_[s_c * 8 + hA] + adh;
        e = (e > 0.f) ? e : NEG * e;
        ex_c = __expf(e);
    }

    float acc[8] = {0.f, 0.f, 0.f, 0.f, 0.f, 0.f, 0.f, 0.f};
    float dsum = 0.f;
    for (int cs = 0; cs < deg; cs += 8) {
        float ex_n = 0.f; int s_n = 0;
        int inext = cs + 8 + j;
        if (inext < deg) {
            s_n = esrc[beg + inext];
            float e = as_[s_n * 8 + hA] + adh;
            e = (e > 0.f) ? e : NEG * e;
            ex_n = __expf(e);
        }
        dsum += ex_c;
        int lim = deg - cs;
        if (lim >= 8) {
#pragma unroll
            for (int it = 0; it < 4; ++it) {
                int slot = it * 2 + rs;
                int s2 = __shfl(s_c, slot * 8);
                float wgt = __shfl(ex_c, slot * 8 + hB);
                half8 hv = *(const half8*)(h + (size_t)s2 * HH + cg * 8);
#pragma unroll
                for (int q = 0; q < 8; ++q) acc[q] += wgt * (float)hv[q];
            }
        } else {
            int itmax = (lim + 1) >> 1;             // wave-uniform
            for (int it = 0; it < itmax; ++it) {
                int slot = it * 2 + rs;
                int s2 = __shfl(s_c, slot * 8);     // all lanes execute
                float wgt = __shfl(ex_c, slot * 8 + hB);
                if (slot < lim) {
                    half8 hv = *(const half8*)(h + (size_t)s2 * HH + cg * 8);
#pragma unroll
                    for (int q = 0; q < 8; ++q) acc[q] += wgt * (float)hv[q];
                }
            }
        }
        ex_c = ex_n; s_c = s_n;
    }
#pragma unroll
    for (int q = 0; q < 8; ++q) acc[q] += __shfl_xor(acc[q], 32);
    dsum += __shfl_xor(dsum, 8); dsum += __shfl_xor(dsum, 16); dsum += __shfl_xor(dsum, 32);
    float denom = __shfl(dsum, hB);
    float inv = 1.f / (denom + 1e-16f);
    if (l < 32) {
        half8 o;
#pragma unroll
        for (int q = 0; q < 8; ++q) {
            float v = acc[q] * inv + bias[cg * 8 + q];
            o[q] = (_Float16)fmaxf(v, 0.f);     // bias + ReLU fused, fp16 out
        }
        *(half8*)(o1h + (size_t)n * HH + cg * 8) = o;
    }
}

// ---------------- layer-2 aggregation (r9/r10-proven, u16 esrc) ----------------

__global__ __launch_bounds__(256) void agg2_kernel(const int* __restrict__ offs,
                                                   const u16* __restrict__ esrc,
                                                   const float* __restrict__ as_,
                                                   const float* __restrict__ ad_,
                                                   const _Float16* __restrict__ h,
                                                   const float* __restrict__ bias,
                                                   float* __restrict__ out) {
    int n = blockIdx.x * 4 + (threadIdx.x >> 6);
    int l = threadIdx.x & 63;
    int beg = offs[n], deg = offs[n + 1] - beg;
    float adn = ad_[n];
    int slot8 = l >> 3;
    int cq = l & 7;

    float ex_c = 0.f; int s_c = 0;
    if (l < deg) {
        s_c = esrc[beg + l];
        float e = as_[s_c] + adn;
        e = (e > 0.f) ? e : NEG * e;
        ex_c = __expf(e);
    }

    float acc[8] = {0.f, 0.f, 0.f, 0.f, 0.f, 0.f, 0.f, 0.f};
    float dsum = 0.f;
    for (int cs = 0; cs < deg; cs += 64) {
        float ex_n = 0.f; int s_n = 0;
        int inext = cs + 64 + l;
        if (inext < deg) {
            s_n = esrc[beg + inext];
            float e = as_[s_n] + adn;
            e = (e > 0.f) ? e : NEG * e;
            ex_n = __expf(e);
        }
        dsum += ex_c;
        int lim = deg - cs; if (lim > 64) lim = 64;
        if (lim >= 64) {
#pragma unroll
            for (int g = 0; g < 8; ++g) {
                int slot = g * 8 + slot8;
                int s2 = __shfl(s_c, slot);
                float wgt = __shfl(ex_c, slot);
                half8 hv = *(const half8*)(h + (size_t)s2 * OUTC + cq * 8);
#pragma unroll
                for (int q = 0; q < 8; ++q) acc[q] += wgt * (float)hv[q];
            }
        } else {
            int gmax = (lim + 7) >> 3;              // wave-uniform
            for (int g = 0; g < gmax; ++g) {
                int slot = g * 8 + slot8;
                int s2 = __shfl(s_c, slot);         // all lanes execute
                float wgt = __shfl(ex_c, slot);
                if (slot < lim) {
                    half8 hv = *(const half8*)(h + (size_t)s2 * OUTC + cq * 8);
#pragma unroll
                    for (int q = 0; q < 8; ++q) acc[q] += wgt * (float)hv[q];
                }
            }
        }
        ex_c = ex_n; s_c = s_n;
    }
#pragma unroll
    for (int q = 0; q < 8; ++q) {
        acc[q] += __shfl_xor(acc[q], 8);
        acc[q] += __shfl_xor(acc[q], 16);
        acc[q] += __shfl_xor(acc[q], 32);
    }
    dsum += __shfl_xor(dsum, 1); dsum += __shfl_xor(dsum, 2); dsum += __shfl_xor(dsum, 4);
    dsum += __shfl_xor(dsum, 8); dsum += __shfl_xor(dsum, 16); dsum += __shfl_xor(dsum, 32);
    float inv = 1.f / (dsum + 1e-16f);
    if (l < 8) {
        int c0 = l * 8;
        float4 o0, o1;
        o0.x = acc[0] * inv + bias[c0 + 0];
        o0.y = acc[1] * inv + bias[c0 + 1];
        o0.z = acc[2] * inv + bias[c0 + 2];
        o0.w = acc[3] * inv + bias[c0 + 3];
        o1.x = acc[4] * inv + bias[c0 + 4];
        o1.y = acc[5] * inv + bias[c0 + 5];
        o1.z = acc[6] * inv + bias[c0 + 6];
        o1.w = acc[7] * inv + bias[c0 + 7];
        *(float4*)(out + (size_t)n * OUTC + c0) = o0;
        *(float4*)(out + (size_t)n * OUTC + c0 + 4) = o1;
    }
}

// ---------------- launcher ----------------

extern "C" void kernel_launch(void* const* d_in, const int* in_sizes, int n_in,
                              void* d_out, int out_size, void* d_ws, size_t ws_size,
                              hipStream_t stream) {
    const float* x    = (const float*)d_in[0];
    const int*   ei   = (const int*)d_in[1];
    const float* W1   = (const float*)d_in[2];
    const float* as1w = (const float*)d_in[3];
    const float* ad1w = (const float*)d_in[4];
    const float* b1   = (const float*)d_in[5];
    const float* W2   = (const float*)d_in[6];
    const float* as2w = (const float*)d_in[7];
    const float* ad2w = (const float*)d_in[8];
    const float* b2   = (const float*)d_in[9];
    float* out = (float*)d_out;

    int N = in_sizes[0] / 128;
    int E = in_sizes[1] / 2;
    int Etot = E + N;
    int nb = (N + 255) / 256;
    int MB = (N + 63) / 64;

    char* p = (char*)d_ws;
    auto alloc = [&](size_t bytes) { char* r = p; p += (bytes + 255) & ~(size_t)255; return r; };
    _Float16* h1  = (_Float16*)alloc((size_t)N * HH * 2);
    _Float16* o1h = (_Float16*)alloc((size_t)N * HH * 2);
    _Float16* h2  = (_Float16*)alloc((size_t)N * OUTC * 2);
    _Float16* W1t = (_Float16*)alloc((size_t)128 * HH * 2);
    _Float16* W2t = (_Float16*)alloc((size_t)HH * OUTC * 2);
    float* a_s1 = (float*)alloc((size_t)N * 8 * 4);
    float* a_d1 = (float*)alloc((size_t)N * 8 * 4);
    float* a_s2 = (float*)alloc((size_t)N * 4);
    float* a_d2 = (float*)alloc((size_t)N * 4);
    int* deg    = (int*)  alloc((size_t)N * 4);
    int* offs   = (int*)  alloc((size_t)(N + 1) * 4);
    int* part   = (int*)  alloc(256 * 4);
    u16* rank   = (u16*)  alloc((size_t)Etot * 2);
    u16* esrc   = (u16*)  alloc((size_t)Etot * 2);

    // CSR by destination (includes self-loops); rank captured during histogram
    hipMemsetAsync(deg, 0, sizeof(int) * N, stream);
    hist_cast<<<(Etot + 255) / 256, 256, 0, stream>>>(ei, E, N, W1, W2, W1t, W2t, deg, rank);
    scan_block<<<nb, 256, 0, stream>>>(deg, offs, part, N);
    scan_finish<<<nb, 256, 0, stream>>>(offs, part, N, nb);
    scatter_kernel<<<(Etot + 255) / 256, 256, 0, stream>>>(ei, E, N, offs, rank, esrc);

    // layer 1: GEMM (scores fused) -> aggregate (bias+ReLU fused, fp16 out)
    mfma_gemm<128, 16, 8, true><<<MB, 256, 0, stream>>>(x, W1t, h1, as1w, ad1w, a_s1, a_d1, N);
    agg1_kernel<<<N / 4, 256, 0, stream>>>(offs, esrc, a_s1, a_d1, h1, b1, o1h);

    // layer 2
    mfma_gemm<256, 4, 1, false><<<MB, 256, 0, stream>>>(o1h, W2t, h2, as2w, ad2w, a_s2, a_d2, N);
    agg2_kernel<<<N / 4, 256, 0, stream>>>(offs, esrc, a_s2, a_d2, h2, b2, out);
}